// Round 1
// baseline (368.891 us; speedup 1.0000x reference)
//
#include <hip/hip_runtime.h>
#include <hip/hip_bf16.h>

#define VOCAB  100000
#define EMB    128
#define NCODES 100000
#define NANC   8

// ---------------------------------------------------------------------------
// Kernel A: P[half][v][c] = sum_k W_emb[v][k] * W_att[half*128 + k][c]
// Tiled f32 GEMM. Block = 256 threads, block tile = 32 rows x 128 cols,
// thread tile = 4x4. LDS: W-half 64 KB + A-tile 16 KB = 80 KB (2 blocks/CU).
// ---------------------------------------------------------------------------
__global__ __launch_bounds__(256) void precompute_gemm(
    const float* __restrict__ W_emb,   // [VOCAB][128]
    const float* __restrict__ W_att,   // [256][128]
    float* __restrict__ P)             // [2][VOCAB][128]
{
    __shared__ float sW[128 * 128];    // W half, row-major [k][c]
    __shared__ float sA[32 * 128];     // A tile, row-major [r][k]

    const int t    = threadIdx.x;
    const int half = blockIdx.y;
    const float* Wh = W_att + (size_t)half * 128 * 128;
    float*       Ph = P    + (size_t)half * VOCAB * 128;

    // Load W half (128x128 f32) into LDS, coalesced float4.
    float4*       sW4 = (float4*)sW;
    const float4* Wg4 = (const float4*)Wh;
    #pragma unroll
    for (int i = 0; i < 16; ++i) sW4[t + 256 * i] = Wg4[t + 256 * i];
    __syncthreads();

    const int tc = t & 31;         // col group: cols 4*tc .. 4*tc+3
    const int tr = t >> 5;         // row group: rows 4*tr .. 4*tr+3
    const int r0 = tr * 4;

    float4* sA4 = (float4*)sA;

    for (int rt = blockIdx.x; rt < VOCAB / 32; rt += gridDim.x) {
        // Stage A tile (32 rows x 128 k) into LDS.
        const float4* Ag4 = (const float4*)(W_emb + (size_t)rt * 32 * 128);
        float4 ld[4];
        #pragma unroll
        for (int i = 0; i < 4; ++i) ld[i] = Ag4[t + 256 * i];
        __syncthreads();   // previous iter's compute finished reading sA
        #pragma unroll
        for (int i = 0; i < 4; ++i) sA4[t + 256 * i] = ld[i];
        __syncthreads();

        float4 acc[4];
        #pragma unroll
        for (int r = 0; r < 4; ++r) acc[r] = make_float4(0.f, 0.f, 0.f, 0.f);

        #pragma unroll 4
        for (int kk = 0; kk < 32; ++kk) {      // 4 k's per iteration
            float4 b[4];
            #pragma unroll
            for (int q = 0; q < 4; ++q) b[q] = sW4[(4 * kk + q) * 32 + tc];
            #pragma unroll
            for (int r = 0; r < 4; ++r) {
                float4 av = sA4[(r0 + r) * 32 + kk];
                float am0 = av.x, am1 = av.y, am2 = av.z, am3 = av.w;
                acc[r].x = fmaf(am0, b[0].x, acc[r].x);
                acc[r].y = fmaf(am0, b[0].y, acc[r].y);
                acc[r].z = fmaf(am0, b[0].z, acc[r].z);
                acc[r].w = fmaf(am0, b[0].w, acc[r].w);
                acc[r].x = fmaf(am1, b[1].x, acc[r].x);
                acc[r].y = fmaf(am1, b[1].y, acc[r].y);
                acc[r].z = fmaf(am1, b[1].z, acc[r].z);
                acc[r].w = fmaf(am1, b[1].w, acc[r].w);
                acc[r].x = fmaf(am2, b[2].x, acc[r].x);
                acc[r].y = fmaf(am2, b[2].y, acc[r].y);
                acc[r].z = fmaf(am2, b[2].z, acc[r].z);
                acc[r].w = fmaf(am2, b[2].w, acc[r].w);
                acc[r].x = fmaf(am3, b[3].x, acc[r].x);
                acc[r].y = fmaf(am3, b[3].y, acc[r].y);
                acc[r].z = fmaf(am3, b[3].z, acc[r].z);
                acc[r].w = fmaf(am3, b[3].w, acc[r].w);
            }
        }

        float4* Pg4 = (float4*)(Ph + (size_t)rt * 32 * 128);
        #pragma unroll
        for (int r = 0; r < 4; ++r) Pg4[(r0 + r) * 32 + tc] = acc[r];
    }
}

// ---------------------------------------------------------------------------
// Kernel B: main attention pass. One wave per code; lane owns 2 columns.
// z = P1[leaf] + P2[anc] + b ; mlp = tanh(z) ; q = mlp . v (wave reduce)
// attn = softmax_a(q) ; out = sum_a attn_a * W_emb[anc_a]
// ---------------------------------------------------------------------------
__device__ __forceinline__ float tanh_fast(float x) {
    float e = __expf(2.0f * x);                 // e^{2x}; inf/0 saturate correctly
    return 1.0f - __fdividef(2.0f, e + 1.0f);
}

__global__ __launch_bounds__(256) void attention_main(
    const float* __restrict__ P,       // [2][VOCAB][128]
    const float* __restrict__ W_emb,   // [VOCAB][128]
    const float* __restrict__ b_att,   // [128]
    const float* __restrict__ v_att,   // [128]
    const int*   __restrict__ leaves,  // [NCODES][8]
    const int*   __restrict__ anc,     // [NCODES][8]
    float*       __restrict__ out)     // [NCODES][128]
{
    const int lane = threadIdx.x & 63;
    const int gw   = blockIdx.x * (blockDim.x >> 6) + (threadIdx.x >> 6);
    const int nw   = gridDim.x * (blockDim.x >> 6);

    const float2* P1 = (const float2*)P;
    const float2* P2 = (const float2*)(P + (size_t)VOCAB * 128);
    const float2* E  = (const float2*)W_emb;

    const float2 bv = ((const float2*)b_att)[lane];
    const float2 vv = ((const float2*)v_att)[lane];

    for (int n = gw; n < NCODES; n += nw) {
        // lanes 0..7 load leaf indices, lanes 8..15 load ancestor indices
        int lidx = 0;
        if (lane < 16)
            lidx = (lane < 8) ? leaves[n * 8 + lane] : anc[n * 8 + (lane & 7)];

        float2 p1[NANC], p2[NANC], em[NANC];
        #pragma unroll
        for (int a = 0; a < NANC; ++a) {
            const int lf = __shfl(lidx, a);
            const int an = __shfl(lidx, 8 + a);
            p1[a] = P1[(size_t)lf * 64 + lane];
            p2[a] = P2[(size_t)an * 64 + lane];
            em[a] = E [(size_t)an * 64 + lane];
        }

        float q[NANC];
        #pragma unroll
        for (int a = 0; a < NANC; ++a) {
            const float zx = p1[a].x + p2[a].x + bv.x;
            const float zy = p1[a].y + p2[a].y + bv.y;
            float qp = tanh_fast(zx) * vv.x + tanh_fast(zy) * vv.y;
            #pragma unroll
            for (int off = 32; off > 0; off >>= 1) qp += __shfl_xor(qp, off);
            q[a] = qp;
        }

        // softmax over 8 ancestors (redundant per lane; all lanes have q[])
        float m = q[0];
        #pragma unroll
        for (int a = 1; a < NANC; ++a) m = fmaxf(m, q[a]);
        float s = 0.f, w[NANC];
        #pragma unroll
        for (int a = 0; a < NANC; ++a) { w[a] = __expf(q[a] - m); s += w[a]; }
        const float inv = __fdividef(1.0f, s);

        float2 o = make_float2(0.f, 0.f);
        #pragma unroll
        for (int a = 0; a < NANC; ++a) {
            const float wa = w[a] * inv;
            o.x = fmaf(wa, em[a].x, o.x);
            o.y = fmaf(wa, em[a].y, o.y);
        }
        ((float2*)out)[(size_t)n * 64 + lane] = o;
    }
}

// ---------------------------------------------------------------------------
extern "C" void kernel_launch(void* const* d_in, const int* in_sizes, int n_in,
                              void* d_out, int out_size, void* d_ws, size_t ws_size,
                              hipStream_t stream) {
    const float* W_emb  = (const float*)d_in[0];
    const float* W_att  = (const float*)d_in[1];
    const float* b_att  = (const float*)d_in[2];
    const float* v_att  = (const float*)d_in[3];
    const int*   leaves = (const int*)d_in[4];
    const int*   anc    = (const int*)d_in[5];
    float*       out    = (float*)d_out;
    float*       P      = (float*)d_ws;   // needs 2*VOCAB*128*4 = 102.4 MB

    // Kernel A: P1/P2 precompute (must run every launch: d_ws is re-poisoned)
    dim3 gridA(625, 2);
    precompute_gemm<<<gridA, 256, 0, stream>>>(W_emb, W_att, P);

    // Kernel B: gather + tanh + softmax + weighted sum
    attention_main<<<1024, 256, 0, stream>>>(P, W_emb, b_att, v_att,
                                             leaves, anc, out);
}

// Round 2
// 231.613 us; speedup vs baseline: 1.5927x; 1.5927x over previous
//
#include <hip/hip_runtime.h>
#include <hip/hip_bf16.h>

#define VOCAB  100000
#define EMB    128
#define NCODES 100000
#define NANC   8
#define PAD    136   // bf16 elems per sBT row: keeps ds_read_b128 16B-aligned

typedef __attribute__((ext_vector_type(8))) short  short8;
typedef __attribute__((ext_vector_type(4))) float  float4v;

__device__ __forceinline__ ushort f2bf(float x) {     // RNE f32 -> bf16 bits
    unsigned u = __float_as_uint(x);
    u += 0x7fffu + ((u >> 16) & 1u);
    return (ushort)(u >> 16);
}
__device__ __forceinline__ float bf2f(ushort h) {
    return __uint_as_float((unsigned)h << 16);
}
__device__ __forceinline__ float tanh_fast(float x) {
    float e = __expf(2.0f * x);               // saturates correctly at +-inf
    return 1.0f - __fdividef(2.0f, e + 1.0f);
}

// ---------------------------------------------------------------------------
// Kernel A: P1 = W_emb @ W_att[:128] + b  (bf16), P2 = W_emb @ W_att[128:]
// (bf16), Ebf = bf16(W_emb). MFMA 16x16x32 bf16. Block = 256 (4 waves),
// 64 rows/block; each wave: 16 rows x 256 cols (both halves share A-frag).
// ---------------------------------------------------------------------------
__global__ __launch_bounds__(256) void precompute(
    const float* __restrict__ W_emb,   // [VOCAB][128]
    const float* __restrict__ W_att,   // [256][128]
    const float* __restrict__ b_att,   // [128]
    ushort* __restrict__ P1, ushort* __restrict__ P2, ushort* __restrict__ Ebf)
{
    __shared__ ushort sBT[256 * PAD];  // B^T: sBT[cc][e], cc=out col, e=k
    const int t = threadIdx.x;

    // Stage W_att -> LDS transposed bf16. thread owns (half tg, col c).
    {
        const int tg = t >> 7;         // 0: rows 0..127 (P1), 1: rows 128..255
        const int c  = t & 127;
        for (int rr = 0; rr < 128; rr += 2) {
            const int r = tg * 128 + rr;
            ushort2 pk;
            pk.x = f2bf(W_att[r * 128 + c]);
            pk.y = f2bf(W_att[(r + 1) * 128 + c]);
            *(ushort2*)&sBT[(tg * 128 + c) * PAD + rr] = pk;
        }
    }
    __syncthreads();

    const int wave = t >> 6, lane = t & 63;
    const int n15 = lane & 15, quad = lane >> 4;
    const long arow = (long)blockIdx.x * 64 + wave * 16 + n15;  // A row (m=n15)
    const long arc  = arow < VOCAB ? arow : 0;

    float4v acc[16];
    #pragma unroll
    for (int i = 0; i < 16; ++i) acc[i] = (float4v)0.0f;

    #pragma unroll
    for (int kt = 0; kt < 4; ++kt) {
        // A-frag: A[m=lane&15][k=quad*8+j]  (m120-verified layout)
        const float4* src = (const float4*)(W_emb + arc * 128 + kt * 32 + quad * 8);
        const float4 a0 = src[0], a1 = src[1];
        short8 af;
        af[0] = f2bf(a0.x); af[1] = f2bf(a0.y); af[2] = f2bf(a0.z); af[3] = f2bf(a0.w);
        af[4] = f2bf(a1.x); af[5] = f2bf(a1.y); af[6] = f2bf(a1.z); af[7] = f2bf(a1.w);
        if (arow < VOCAB)   // free bf16 copy of W_emb for kernel B
            *(short8*)(void*)(Ebf + arow * 128 + kt * 32 + quad * 8) = af;
        #pragma unroll
        for (int nt = 0; nt < 16; ++nt) {
            // B-frag: B[k=quad*8+j][n=lane&15] = sBT[nt*16+n15][kt*32+quad*8+j]
            short8 bfr = *(const short8*)&sBT[(nt * 16 + n15) * PAD + kt * 32 + quad * 8];
            acc[nt] = __builtin_amdgcn_mfma_f32_16x16x32_bf16(af, bfr, acc[nt], 0, 0, 0);
        }
    }

    // Epilogue. C/D: col = lane&15, row = quad*4 + reg (m89-verified).
    float bv[8];
    #pragma unroll
    for (int nt = 0; nt < 8; ++nt) bv[nt] = b_att[nt * 16 + n15];

    const long srow0 = (long)blockIdx.x * 64 + wave * 16 + quad * 4;
    #pragma unroll
    for (int nt = 0; nt < 16; ++nt) {
        const int cc = nt * 16 + n15;
        #pragma unroll
        for (int i = 0; i < 4; ++i) {
            const long gr = srow0 + i;
            if (gr < VOCAB) {
                const float v = acc[nt][i] + (nt < 8 ? bv[nt] : 0.0f);
                const ushort h = f2bf(v);
                if (nt < 8) P1[gr * 128 + cc]       = h;   // b folded into P1
                else        P2[gr * 128 + cc - 128] = h;
            }
        }
    }
}

// ---------------------------------------------------------------------------
// Kernel B: wave = 2 codes (half-wave each), lane owns 4 cols (ushort4 = 8B
// gathers). z = P1[leaf] + P2[anc]; q = tanh(z).v (5-stage butterfly);
// softmax over 8; out = sum attn * E[anc].
// ---------------------------------------------------------------------------
__global__ __launch_bounds__(256) void attention_main(
    const ushort* __restrict__ P1, const ushort* __restrict__ P2,
    const ushort* __restrict__ Ebf,
    const float* __restrict__ v_att,
    const int*   __restrict__ leaves, const int* __restrict__ anc,
    float*       __restrict__ out)
{
    const int lane = threadIdx.x & 63;
    const int wave = threadIdx.x >> 6;
    const int h    = lane >> 5, l32 = lane & 31;
    const long n   = ((long)blockIdx.x * 4 + wave) * 2 + h;   // grid exact

    const float4 vv = *(const float4*)(v_att + l32 * 4);

    // lanes l32<8 of each half: leaf idx; l32 in 8..15: ancestor idx
    int lidx = 0;
    if (l32 < 16)
        lidx = (l32 < 8) ? leaves[n * 8 + l32] : anc[n * 8 + (l32 & 7)];

    ushort4 emb[NANC];
    float q[NANC];
    #pragma unroll
    for (int a = 0; a < NANC; ++a) {
        const int lf = __shfl(lidx, h * 32 + a);
        const int an = __shfl(lidx, h * 32 + 8 + a);
        const ushort4 r1 = *(const ushort4*)(P1  + (size_t)lf * 128 + l32 * 4);
        const ushort4 r2 = *(const ushort4*)(P2  + (size_t)an * 128 + l32 * 4);
        emb[a]           = *(const ushort4*)(Ebf + (size_t)an * 128 + l32 * 4);
        const float z0 = bf2f(r1.x) + bf2f(r2.x);
        const float z1 = bf2f(r1.y) + bf2f(r2.y);
        const float z2 = bf2f(r1.z) + bf2f(r2.z);
        const float z3 = bf2f(r1.w) + bf2f(r2.w);
        float qp = tanh_fast(z0) * vv.x + tanh_fast(z1) * vv.y
                 + tanh_fast(z2) * vv.z + tanh_fast(z3) * vv.w;
        qp += __shfl_xor(qp, 1); qp += __shfl_xor(qp, 2);
        qp += __shfl_xor(qp, 4); qp += __shfl_xor(qp, 8);
        qp += __shfl_xor(qp, 16);                 // stays within 32-lane half
        q[a] = qp;
    }

    float m = q[0];
    #pragma unroll
    for (int a = 1; a < NANC; ++a) m = fmaxf(m, q[a]);
    float s = 0.f, w[NANC];
    #pragma unroll
    for (int a = 0; a < NANC; ++a) { w[a] = __expf(q[a] - m); s += w[a]; }
    const float inv = __fdividef(1.0f, s);

    float4 o = make_float4(0.f, 0.f, 0.f, 0.f);
    #pragma unroll
    for (int a = 0; a < NANC; ++a) {
        const float wa = w[a] * inv;
        o.x = fmaf(wa, bf2f(emb[a].x), o.x);
        o.y = fmaf(wa, bf2f(emb[a].y), o.y);
        o.z = fmaf(wa, bf2f(emb[a].z), o.z);
        o.w = fmaf(wa, bf2f(emb[a].w), o.w);
    }
    *(float4*)(out + (size_t)n * 128 + l32 * 4) = o;
}

// ---------------------------------------------------------------------------
extern "C" void kernel_launch(void* const* d_in, const int* in_sizes, int n_in,
                              void* d_out, int out_size, void* d_ws, size_t ws_size,
                              hipStream_t stream) {
    const float* W_emb  = (const float*)d_in[0];
    const float* W_att  = (const float*)d_in[1];
    const float* b_att  = (const float*)d_in[2];
    const float* v_att  = (const float*)d_in[3];
    const int*   leaves = (const int*)d_in[4];
    const int*   anc    = (const int*)d_in[5];
    float*       out    = (float*)d_out;

    ushort* P1  = (ushort*)d_ws;                       // 25.6 MB
    ushort* P2  = P1 + (size_t)VOCAB * 128;            // 25.6 MB
    ushort* Ebf = P2 + (size_t)VOCAB * 128;            // 25.6 MB (76.8 total)

    precompute<<<(VOCAB + 63) / 64, 256, 0, stream>>>(W_emb, W_att, b_att,
                                                      P1, P2, Ebf);
    attention_main<<<NCODES / 8, 256, 0, stream>>>(P1, P2, Ebf, v_att,
                                                   leaves, anc, out);
}